// Round 8
// baseline (123.918 us; speedup 1.0000x reference)
//
#include <hip/hip_runtime.h>

#define HH 256
#define WW 512
#define CC 64
#define CO 16
#define DD 48            // MAX_DISPARITY
#define ND (DD + 1)      // 49 disparity planes

typedef float f32x4 __attribute__((ext_vector_type(4)));

// Kernel 1: per-pixel 16x64 matvec; bias folded into L.
__global__ __launch_bounds__(256) void lr_project(
    const float* __restrict__ left, const float* __restrict__ right,
    const float* __restrict__ Wop, const float* __restrict__ bop,
    float* __restrict__ Lout, float* __restrict__ Rout)
{
    const int tid = blockIdx.x * blockDim.x + threadIdx.x;  // 0 .. H*W-1
    const int x = tid & (WW - 1);
    const int y = tid >> 9;   // /512

    float accL[CO], accR[CO];
#pragma unroll
    for (int o = 0; o < CO; ++o) { accL[o] = 0.0f; accR[o] = 0.0f; }

#pragma unroll 4
    for (int c = 0; c < CC; ++c) {
        const float l = left [(c * HH + y) * WW + x];
        const float r = right[(c * HH + y) * WW + x];
#pragma unroll
        for (int o = 0; o < CO; ++o) {
            accL[o] += Wop[o * (2 * CC) + c]      * l;
            accR[o] += Wop[o * (2 * CC) + CC + c] * r;
        }
    }

#pragma unroll
    for (int o = 0; o < CO; ++o) {
        Lout[(o * HH + y) * WW + x] = accL[o] + bop[o];   // bias folded here
        Rout[(o * HH + y) * WW + x] = accR[o];
    }
}

// Kernel 2: block = one (o,d) output plane. o,d,masks are block/thread
// constants; inner loop is a pure monotone store stream (4 KB/thread stride)
// with two L2-resident loads per store. XCD g owns o in {2g, 2g+1} so each
// XCD's L2 holds exactly its 4 MB of L/R.
__global__ __launch_bounds__(256) void assemble_plane(
    const float* __restrict__ L, const float* __restrict__ R,
    float* __restrict__ out)
{
    // blockIdx.x = g + 8*j, g = XCD slot (0..7), j = 0..97
    const int g = blockIdx.x & 7;
    const int j = blockIdx.x >> 3;          // 0..97
    const int o = 2 * g + (j / ND);         // 0..15
    const int d = j % ND;                   // 0..48
    const int od = o * ND + d;

    const int t  = threadIdx.x;
    const int x4 = t & 127;
    const int y0 = t >> 7;                  // 0 or 1
    const int x  = x4 * 4;

    // per-thread constant boundary masks
    const float m0 = (x + 0 >= d) ? 1.0f : 0.0f;
    const float m1 = (x + 1 >= d) ? 1.0f : 0.0f;
    const float m2 = (x + 2 >= d) ? 1.0f : 0.0f;
    const float m3 = (x + 3 >= d) ? 1.0f : 0.0f;

    const float* Lp = &L[(o * HH + y0) * WW + x];
    const float* Rp = Lp + (R - L) - d;     // speculative: may dip into L region (valid mem, masked)
    float*       op = &out[((size_t)od * HH + y0) * WW + x];

#pragma unroll 4
    for (int k = 0; k < HH / 2; ++k) {      // 128 iterations, y += 2 per iter
        const f32x4 lv = *reinterpret_cast<const f32x4*>(Lp);   // L + b (aligned)
        f32x4 rv;                                               // 4B-aligned 16B load
        __builtin_memcpy(&rv, Rp, sizeof(rv));

        f32x4 ov;
        ov.x = lv.x + m0 * rv.x;
        ov.y = lv.y + m1 * rv.y;
        ov.z = lv.z + m2 * rv.z;
        ov.w = lv.w + m3 * rv.w;
        __builtin_nontemporal_store(ov, reinterpret_cast<f32x4*>(op));

        Lp += 2 * WW;
        Rp += 2 * WW;
        op += 2 * WW;
    }
}

extern "C" void kernel_launch(void* const* d_in, const int* in_sizes, int n_in,
                              void* d_out, int out_size, void* d_ws, size_t ws_size,
                              hipStream_t stream) {
    const float* left  = (const float*)d_in[0];
    const float* right = (const float*)d_in[1];
    const float* Wop   = (const float*)d_in[2];
    const float* bop   = (const float*)d_in[3];
    float* out = (float*)d_out;

    float* Lws = (float*)d_ws;                      // CO*H*W floats = 8 MB (holds L+b)
    float* Rws = Lws + (size_t)CO * HH * WW;        // next 8 MB

    lr_project<<<(HH * WW) / 256, 256, 0, stream>>>(left, right, Wop, bop, Lws, Rws);

    // 784 blocks: one per (o,d) plane, XCD-clustered by o
    assemble_plane<<<CO * ND, 256, 0, stream>>>(Lws, Rws, out);
}